// Round 6
// baseline (247.366 us; speedup 1.0000x reference)
//
#include <hip/hip_runtime.h>

#define T_STEPS 128
#define B_TOTAL 65536
#define BLOCK 256
#define NBLOCKS (B_TOTAL / BLOCK)   // 256 blocks -> 1 block/CU
#define CH 16                        // timesteps per staged chunk
#define NCH (T_STEPS / CH)           // 8 chunks
#define R4S 13                       // row stride in float4 (52 floats), 12 used + 1 pad
#define FPT 12                       // float4 loads/thread/chunk = 256*48/(4*256)

#define LOG2E 1.44269504088896f

typedef __attribute__((ext_vector_type(2))) float f2;

__device__ __forceinline__ float fast_rcp(float x) {
    return __builtin_amdgcn_rcpf(x);
}
__device__ __forceinline__ float fast_exp2(float x) {
    return __builtin_amdgcn_exp2f(x);
}

__global__ __launch_bounds__(BLOCK, 1) void lstm_nll_main(
    const float* __restrict__ x,       // (B, T, 3)
    const float* __restrict__ h0,      // (B)
    const float* __restrict__ c0,      // (B)
    const float* __restrict__ target,  // (B, 3)
    const float* __restrict__ W_ih,    // (4,3)
    const float* __restrict__ W_hh,    // (4,1)
    const float* __restrict__ b_ih,    // (4)
    const float* __restrict__ b_hh,    // (4)
    const float* __restrict__ W_mean,  // (3,128)
    const float* __restrict__ b_mean,  // (3)
    const float* __restrict__ W_var,   // (6,128)
    const float* __restrict__ b_var,   // (6)
    float* __restrict__ partial)       // (NBLOCKS)
{
    __shared__ __align__(16) float4 lds_x4[BLOCK * R4S];  // 53248 B
    __shared__ float4 wpack4[T_STEPS * 3];                // 6144 B
    __shared__ float  wavesum[BLOCK / 64];

    const int tid = threadIdx.x;

    // pack projection weights: per t: {m0,m1,m2,e0},{e1,e2,e3,e4},{e5,0,0,0}
    for (int idx = tid; idx < T_STEPS * 3; idx += BLOCK) {
        const int t = idx / 3;
        const int k = idx - t * 3;
        float4 v;
        if (k == 0)      v = make_float4(W_mean[0*T_STEPS+t], W_mean[1*T_STEPS+t],
                                         W_mean[2*T_STEPS+t], W_var[0*T_STEPS+t]);
        else if (k == 1) v = make_float4(W_var[1*T_STEPS+t], W_var[2*T_STEPS+t],
                                         W_var[3*T_STEPS+t], W_var[4*T_STEPS+t]);
        else             v = make_float4(W_var[5*T_STEPS+t], 0.f, 0.f, 0.f);
        wpack4[idx] = v;
    }

    const int b = blockIdx.x * BLOCK + tid;
    const float* xb = x + (size_t)b * (T_STEPS * 3);

    // hoist epilogue-only loads so their latency overlaps the whole kernel
    const float t0 = target[b*3+0], t1 = target[b*3+1], t2 = target[b*3+2];

    // ---- rotation from rows 127,126,125 (one-time scattered loads) ----
    const float v1x = xb[127*3+0], v1y = xb[127*3+1], v1z = xb[127*3+2];
    const float v2x = xb[126*3+0], v2y = xb[126*3+1], v2z = xb[126*3+2];
    const float v3x = xb[125*3+0], v3y = xb[125*3+1], v3z = xb[125*3+2];

    const float inv1 = rsqrtf(v1x*v1x + v1y*v1y + v1z*v1z);
    const float b1x = v1x*inv1, b1y = v1y*inv1, b1z = v1z*inv1;
    const float dp  = v2x*b1x + v2y*b1y + v2z*b1z;
    const float a2x = v2x - dp*b1x, a2y = v2y - dp*b1y, a2z = v2z - dp*b1z;
    const float inv2 = rsqrtf(a2x*a2x + a2y*a2y + a2z*a2z);
    const float b2x = a2x*inv2, b2y = a2y*inv2, b2z = a2z*inv2;
    float b3x = b1y*b2z - b1z*b2y;
    float b3y = b1z*b2x - b1x*b2z;
    float b3z = b1x*b2y - b1y*b2x;
    const float sgn = (v3x*b3x + v3y*b3y + v3z*b3z) > 0.0f ? 1.0f : -1.0f;
    b3x *= sgn; b3y *= sgn; b3z *= sgn;

    // ---- gate weights folded with rotation AND -log2e scaling ----
    // gA = (i,f) scaled by -log2e ; gB = (g,o), g scaled by -2log2e, o by -log2e
    const float wi00 = W_ih[0], wi01 = W_ih[1],  wi02 = W_ih[2];
    const float wi10 = W_ih[3], wi11 = W_ih[4],  wi12 = W_ih[5];
    const float wi20 = W_ih[6], wi21 = W_ih[7],  wi22 = W_ih[8];
    const float wi30 = W_ih[9], wi31 = W_ih[10], wi32 = W_ih[11];
    const float s1 = -LOG2E, s2 = -2.0f * LOG2E;

    const f2 wAx = { s1*(wi00*b1x + wi01*b2x + wi02*b3x),
                     s1*(wi10*b1x + wi11*b2x + wi12*b3x) };
    const f2 wAy = { s1*(wi00*b1y + wi01*b2y + wi02*b3y),
                     s1*(wi10*b1y + wi11*b2y + wi12*b3y) };
    const f2 wAz = { s1*(wi00*b1z + wi01*b2z + wi02*b3z),
                     s1*(wi10*b1z + wi11*b2z + wi12*b3z) };
    const f2 wBx = { s2*(wi20*b1x + wi21*b2x + wi22*b3x),
                     s1*(wi30*b1x + wi31*b2x + wi32*b3x) };
    const f2 wBy = { s2*(wi20*b1y + wi21*b2y + wi22*b3y),
                     s1*(wi30*b1y + wi31*b2y + wi32*b3y) };
    const f2 wBz = { s2*(wi20*b1z + wi21*b2z + wi22*b3z),
                     s1*(wi30*b1z + wi31*b2z + wi32*b3z) };
    const f2 wAh = { s1*W_hh[0], s1*W_hh[1] };
    const f2 wBh = { s2*W_hh[2], s1*W_hh[3] };
    const f2 bgA = { s1*(b_ih[0] + b_hh[0]), s1*(b_ih[1] + b_hh[1]) };
    const f2 bgB = { s2*(b_ih[2] + b_hh[2]), s1*(b_ih[3] + b_hh[3]) };

    float h = h0[b];
    float c = c0[b];
    f2 P0 = {0.f, 0.f}, P1 = {0.f, 0.f}, P2 = {0.f, 0.f}, P3 = {0.f, 0.f};
    float e5a = 0.f;

    // ---- cooperative staging plan (coalesced global -> LDS) ----
    const float4* xg4 = (const float4*)(x + (size_t)blockIdx.x * BLOCK * (T_STEPS * 3));
    int ldsidx[FPT];    // float4 index in lds_x4
    int gidx[FPT];      // float4 index in block slab
    #pragma unroll
    for (int j = 0; j < FPT; ++j) {
        const int f = j * BLOCK + tid;       // 0..3071
        const int r = f / FPT;               // row 0..255
        const int cc = f - r * FPT;          // 0..11
        ldsidx[j] = r * R4S + cc;
        gidx[j]   = r * (T_STEPS * 3 / 4) + cc;   // r*96 + cc
    }

    float4 pre[FPT];
    #pragma unroll
    for (int j = 0; j < FPT; ++j) pre[j] = xg4[gidx[j]];

    const float4* myrow4 = &lds_x4[tid * R4S];

    for (int tc = 0; tc < NCH; ++tc) {
        __syncthreads();
        #pragma unroll
        for (int j = 0; j < FPT; ++j) {
            lds_x4[ldsidx[j]] = pre[j];              // ds_write_b128, ~stride-1
        }
        __syncthreads();

        // ---- bulk row read: whole chunk's x into registers (batched latency) ----
        float4 xr[FPT];
        #pragma unroll
        for (int j = 0; j < FPT; ++j) xr[j] = myrow4[j];   // 12x ds_read_b128
        const float* xf = (const float*)xr;                 // 48 floats, reg-resident

        // ---- prefetch next chunk from global (overlaps compute) ----
        if (tc + 1 < NCH) {
            const int cb = (tc + 1) * FPT;
            #pragma unroll
            for (int j = 0; j < FPT; ++j) pre[j] = xg4[gidx[j] + cb];
        }

        // ---- serial recurrence + merged projection accumulate ----
        #pragma unroll
        for (int s = 0; s < CH; ++s) {
            const float xx = xf[s*3+0], xy = xf[s*3+1], xz = xf[s*3+2];
            const f2 X = { xx, xx };
            const f2 Y = { xy, xy };
            const f2 Z = { xz, xz };
            const f2 H = { h, h };
            const f2 gA = wAx*X + wAy*Y + wAz*Z + wAh*H + bgA;  // (i,f) scaled
            const f2 gB = wBx*X + wBy*Y + wBz*Z + wBh*H + bgB;  // (g,o) scaled
            const float u = fast_exp2(gA.x);   // e^{-gi}
            const float a = fast_exp2(gA.y);   // e^{-gf}
            const float v = fast_exp2(gB.x);   // e^{-2gg}
            const float z = fast_exp2(gB.y);   // e^{-go}
            // c' = [c(1+u)(1+v) + (1-v)(1+a)] / [(1+a)(1+u)(1+v)]
            const float U = 1.0f + u, A = 1.0f + a, V = 1.0f + v;
            const float Q = U * V;
            const float num = __builtin_fmaf(c, Q, (2.0f - V) * A);
            const float den = Q * A;
            c = num * fast_rcp(den);
            // h = (1-w)/[(1+z)(1+w)], w = e^{-2c}, clamp exp2 arg
            const float wm_raw = c * (-2.0f * LOG2E);
            const float wm = fminf(fmaxf(wm_raw, -126.0f), 126.0f);
            const float w = fast_exp2(wm);
            const float W = 1.0f + w;
            h = (2.0f - W) * fast_rcp((1.0f + z) * W);
            // projection accumulate (independent filler for the serial chain)
            const int t = tc * CH + s;
            const float4 w0 = wpack4[t*3+0];
            const float4 w1 = wpack4[t*3+1];
            const float4 w2 = wpack4[t*3+2];
            const f2 Hv = { h, h };
            P0 += ((f2){w0.x, w0.y}) * Hv;
            P1 += ((f2){w0.z, w0.w}) * Hv;
            P2 += ((f2){w1.x, w1.y}) * Hv;
            P3 += ((f2){w1.z, w1.w}) * Hv;
            e5a += w2.x * h;
        }
    }

    // ---- epilogue: NLL (division-free) ----
    const float m0 = P0.x + b_mean[0];
    const float m1 = P0.y + b_mean[1];
    const float m2 = P1.x + b_mean[2];
    const float e0 = P1.y + b_var[0];
    const float e1 = P2.x + b_var[1];
    const float e2 = P2.y + b_var[2];
    const float e3 = P3.x + b_var[3];
    const float e4 = P3.y + b_var[4];
    const float e5 = e5a  + b_var[5];

    const float dv0 = fast_exp2(e3 * LOG2E);
    const float dv1 = fast_exp2(e4 * LOG2E);
    const float dv2 = fast_exp2(e5 * LOG2E);

    const float rt0 = b1x*t0 + b1y*t1 + b1z*t2;
    const float rt1 = b2x*t0 + b2y*t1 + b2z*t2;
    const float rt2 = b3x*t0 + b3y*t1 + b3z*t2;

    const float d0 = m0 - rt0, d1 = m1 - rt1, d2 = m2 - rt2;
    const float y0 = d0;
    const float y1 = d1 - e0 * y0;
    const float y2 = d2 - e1 * y0 - e2 * y1;
    const float quad = y0*y0*fast_rcp(dv0) + y1*y1*fast_rcp(dv1)
                     + y2*y2*fast_rcp(dv2);

    float contrib = 0.5f * (dv0 + dv1 + dv2) + 0.5f * quad;

    #pragma unroll
    for (int off = 32; off > 0; off >>= 1)
        contrib += __shfl_down(contrib, off, 64);
    const int lane = tid & 63, wid = tid >> 6;
    if (lane == 0) wavesum[wid] = contrib;
    __syncthreads();
    if (tid == 0) {
        float s = 0.f;
        #pragma unroll
        for (int w = 0; w < BLOCK / 64; ++w) s += wavesum[w];
        partial[blockIdx.x] = s;
    }
}

__global__ __launch_bounds__(256) void lstm_nll_finalize(
    const float* __restrict__ partial, float* __restrict__ out, int n)
{
    const int tid = threadIdx.x;
    float s = 0.0f;
    for (int i = tid; i < n; i += 256) s += partial[i];
    #pragma unroll
    for (int off = 32; off > 0; off >>= 1)
        s += __shfl_down(s, off, 64);
    __shared__ float wavesum[4];
    const int lane = tid & 63, wid = tid >> 6;
    if (lane == 0) wavesum[wid] = s;
    __syncthreads();
    if (tid == 0) {
        out[0] = (wavesum[0] + wavesum[1] + wavesum[2] + wavesum[3]) *
                 (1.0f / (float)B_TOTAL);
    }
}

extern "C" void kernel_launch(void* const* d_in, const int* in_sizes, int n_in,
                              void* d_out, int out_size, void* d_ws, size_t ws_size,
                              hipStream_t stream) {
    const float* x      = (const float*)d_in[0];
    const float* h0     = (const float*)d_in[1];
    const float* c0     = (const float*)d_in[2];
    const float* target = (const float*)d_in[3];
    const float* W_ih   = (const float*)d_in[4];
    const float* W_hh   = (const float*)d_in[5];
    const float* b_ih   = (const float*)d_in[6];
    const float* b_hh   = (const float*)d_in[7];
    const float* W_mean = (const float*)d_in[8];
    const float* b_mean = (const float*)d_in[9];
    const float* W_var  = (const float*)d_in[10];
    const float* b_var  = (const float*)d_in[11];

    float* partial = (float*)d_ws;  // NBLOCKS floats

    lstm_nll_main<<<NBLOCKS, BLOCK, 0, stream>>>(
        x, h0, c0, target, W_ih, W_hh, b_ih, b_hh,
        W_mean, b_mean, W_var, b_var, partial);
    lstm_nll_finalize<<<1, 256, 0, stream>>>(partial, (float*)d_out, NBLOCKS);
}

// Round 7
// 182.692 us; speedup vs baseline: 1.3540x; 1.3540x over previous
//
#include <hip/hip_runtime.h>

#define T_STEPS 128
#define B_TOTAL 65536
#define BLOCK 256
#define NBLOCKS (B_TOTAL / BLOCK)   // 256 blocks -> 1 block/CU
#define CH 16                        // timesteps per chunk
#define NCH (T_STEPS / CH)           // 8 chunks
#define FPT 12                       // float4 per thread per chunk (16 steps * 3 / 4)

#define LOG2E 1.44269504088896f

typedef __attribute__((ext_vector_type(2))) float f2;

__device__ __forceinline__ float fast_rcp(float x) {
    return __builtin_amdgcn_rcpf(x);
}
__device__ __forceinline__ float fast_exp2(float x) {
    return __builtin_amdgcn_exp2f(x);
}

// ---- compile-time unroll machinery (guarantees constant indices -> SROA) ----
template<int I> struct IC { static constexpr int value = I; };

template<int S, int E, typename F>
__device__ __forceinline__ void sloop(F&& f) {
    if constexpr (S < E) {
        f(IC<S>{});
        sloop<S + 1, E>(f);
    }
}

// compile-time component extraction from a float4 register array (no pointers!)
template<int I>
__device__ __forceinline__ float f4get(const float4 (&a)[FPT]) {
    constexpr int q = I >> 2;
    constexpr int r = I & 3;
    if constexpr (r == 0) return a[q].x;
    else if constexpr (r == 1) return a[q].y;
    else if constexpr (r == 2) return a[q].z;
    else return a[q].w;
}

__global__ __launch_bounds__(BLOCK, 1) void lstm_nll_main(
    const float* __restrict__ x,       // (B, T, 3)
    const float* __restrict__ h0,      // (B)
    const float* __restrict__ c0,      // (B)
    const float* __restrict__ target,  // (B, 3)
    const float* __restrict__ W_ih,    // (4,3)
    const float* __restrict__ W_hh,    // (4,1)
    const float* __restrict__ b_ih,    // (4)
    const float* __restrict__ b_hh,    // (4)
    const float* __restrict__ W_mean,  // (3,128)
    const float* __restrict__ b_mean,  // (3)
    const float* __restrict__ W_var,   // (6,128)
    const float* __restrict__ b_var,   // (6)
    float* __restrict__ partial)       // (NBLOCKS)
{
    __shared__ float4 wpack4[T_STEPS * 3];   // 6144 B
    __shared__ float  wavesum[BLOCK / 64];

    const int tid = threadIdx.x;

    // pack projection weights: per t: {m0,m1,m2,e0},{e1,e2,e3,e4},{e5,0,0,0}
    for (int idx = tid; idx < T_STEPS * 3; idx += BLOCK) {
        const int t = idx / 3;
        const int k = idx - t * 3;
        float4 v;
        if (k == 0)      v = make_float4(W_mean[0*T_STEPS+t], W_mean[1*T_STEPS+t],
                                         W_mean[2*T_STEPS+t], W_var[0*T_STEPS+t]);
        else if (k == 1) v = make_float4(W_var[1*T_STEPS+t], W_var[2*T_STEPS+t],
                                         W_var[3*T_STEPS+t], W_var[4*T_STEPS+t]);
        else             v = make_float4(W_var[5*T_STEPS+t], 0.f, 0.f, 0.f);
        wpack4[idx] = v;
    }

    const int b = blockIdx.x * BLOCK + tid;
    const float* xb = x + (size_t)b * (T_STEPS * 3);
    const float4* xg4row = (const float4*)xb;   // 96 float4 per row, 16B aligned

    // hoist scalar loads early (latency overlaps weight prep)
    const float hh0 = h0[b];
    const float cc0 = c0[b];
    const float t0 = target[b*3+0], t1 = target[b*3+1], t2 = target[b*3+2];

    // ---- rotation from rows 127,126,125 ----
    const float v1x = xb[127*3+0], v1y = xb[127*3+1], v1z = xb[127*3+2];
    const float v2x = xb[126*3+0], v2y = xb[126*3+1], v2z = xb[126*3+2];
    const float v3x = xb[125*3+0], v3y = xb[125*3+1], v3z = xb[125*3+2];

    const float inv1 = rsqrtf(v1x*v1x + v1y*v1y + v1z*v1z);
    const float b1x = v1x*inv1, b1y = v1y*inv1, b1z = v1z*inv1;
    const float dp  = v2x*b1x + v2y*b1y + v2z*b1z;
    const float a2x = v2x - dp*b1x, a2y = v2y - dp*b1y, a2z = v2z - dp*b1z;
    const float inv2 = rsqrtf(a2x*a2x + a2y*a2y + a2z*a2z);
    const float b2x = a2x*inv2, b2y = a2y*inv2, b2z = a2z*inv2;
    float b3x = b1y*b2z - b1z*b2y;
    float b3y = b1z*b2x - b1x*b2z;
    float b3z = b1x*b2y - b1y*b2x;
    const float sgn = (v3x*b3x + v3y*b3y + v3z*b3z) > 0.0f ? 1.0f : -1.0f;
    b3x *= sgn; b3y *= sgn; b3z *= sgn;

    // ---- gate weights folded with rotation AND -log2e scaling ----
    // gA = (i,f) scaled by -log2e ; gB = (g,o): g scaled by -2log2e, o by -log2e
    const float wi00 = W_ih[0], wi01 = W_ih[1],  wi02 = W_ih[2];
    const float wi10 = W_ih[3], wi11 = W_ih[4],  wi12 = W_ih[5];
    const float wi20 = W_ih[6], wi21 = W_ih[7],  wi22 = W_ih[8];
    const float wi30 = W_ih[9], wi31 = W_ih[10], wi32 = W_ih[11];
    const float s1 = -LOG2E, s2 = -2.0f * LOG2E;

    const f2 wAx = { s1*(wi00*b1x + wi01*b2x + wi02*b3x),
                     s1*(wi10*b1x + wi11*b2x + wi12*b3x) };
    const f2 wAy = { s1*(wi00*b1y + wi01*b2y + wi02*b3y),
                     s1*(wi10*b1y + wi11*b2y + wi12*b3y) };
    const f2 wAz = { s1*(wi00*b1z + wi01*b2z + wi02*b3z),
                     s1*(wi10*b1z + wi11*b2z + wi12*b3z) };
    const f2 wBx = { s2*(wi20*b1x + wi21*b2x + wi22*b3x),
                     s1*(wi30*b1x + wi31*b2x + wi32*b3x) };
    const f2 wBy = { s2*(wi20*b1y + wi21*b2y + wi22*b3y),
                     s1*(wi30*b1y + wi31*b2y + wi32*b3y) };
    const f2 wBz = { s2*(wi20*b1z + wi21*b2z + wi22*b3z),
                     s1*(wi30*b1z + wi31*b2z + wi32*b3z) };
    const f2 wAh = { s1*W_hh[0], s1*W_hh[1] };
    const f2 wBh = { s2*W_hh[2], s1*W_hh[3] };
    const f2 bgA = { s1*(b_ih[0] + b_hh[0]), s1*(b_ih[1] + b_hh[1]) };
    const f2 bgB = { s2*(b_ih[2] + b_hh[2]), s1*(b_ih[3] + b_hh[3]) };

    float h = hh0;
    float c = cc0;
    f2 P0 = {0.f, 0.f}, P1 = {0.f, 0.f}, P2 = {0.f, 0.f}, P3 = {0.f, 0.f};
    float e5a = 0.f;

    __syncthreads();   // wpack4 visible before first use

    // ---- double-buffered register prefetch of this thread's own row ----
    float4 bufA[FPT], bufB[FPT];

    auto loadbuf = [&](float4 (&buf)[FPT], auto ck) {
        constexpr int chunk = decltype(ck)::value;
        #pragma unroll
        for (int j = 0; j < FPT; ++j) buf[j] = xg4row[chunk * FPT + j];
    };

    auto do_chunk = [&](const float4 (&buf)[FPT], auto tb) {
        constexpr int tbase = decltype(tb)::value;
        sloop<0, CH>([&](auto ics) {
            constexpr int s = decltype(ics)::value;
            const float xx = f4get<3*s+0>(buf);
            const float xy = f4get<3*s+1>(buf);
            const float xz = f4get<3*s+2>(buf);
            const f2 X = { xx, xx };
            const f2 Y = { xy, xy };
            const f2 Z = { xz, xz };
            // x-only part first (independent of h), h enters via ONE pk_fma
            const f2 xdA = wAx*X + wAy*Y + wAz*Z + bgA;
            const f2 xdB = wBx*X + wBy*Y + wBz*Z + bgB;
            const f2 H = { h, h };
            const f2 gA = wAh*H + xdA;   // (i,f) scaled
            const f2 gB = wBh*H + xdB;   // (g,o) scaled
            const float u = fast_exp2(gA.x);   // e^{-gi}
            const float a = fast_exp2(gA.y);   // e^{-gf}
            const float v = fast_exp2(gB.x);   // e^{-2gg}
            const float z = fast_exp2(gB.y);   // e^{-go}
            // c' = [c(1+u)(1+v) + (1-v)(1+a)] / [(1+a)(1+u)(1+v)]
            const float U = 1.0f + u, A = 1.0f + a, V = 1.0f + v;
            const float Q = U * V;
            const float num = __builtin_fmaf(c, Q, (2.0f - V) * A);
            const float den = Q * A;
            c = num * fast_rcp(den);
            // h = (1-w)/[(1+z)(1+w)], w = e^{-2c}; upper clamp avoids inf*0
            const float wm = fminf(c * (-2.0f * LOG2E), 126.0f);
            const float w = fast_exp2(wm);
            const float W = 1.0f + w;
            h = (2.0f - W) * fast_rcp((1.0f + z) * W);
            // projection accumulate (independent filler)
            const float4 w0 = wpack4[(tbase + s)*3 + 0];
            const float4 w1 = wpack4[(tbase + s)*3 + 1];
            const float4 w2 = wpack4[(tbase + s)*3 + 2];
            const f2 Hv = { h, h };
            P0 += ((f2){w0.x, w0.y}) * Hv;
            P1 += ((f2){w0.z, w0.w}) * Hv;
            P2 += ((f2){w1.x, w1.y}) * Hv;
            P3 += ((f2){w1.z, w1.w}) * Hv;
            e5a += w2.x * h;
        });
    };

    loadbuf(bufA, IC<0>{});
    loadbuf(bufB, IC<1>{});

    sloop<0, NCH>([&](auto icc) {
        constexpr int tc = decltype(icc)::value;
        if constexpr ((tc & 1) == 0) {
            do_chunk(bufA, IC<tc * CH>{});
            if constexpr (tc + 2 < NCH) loadbuf(bufA, IC<tc + 2>{});
        } else {
            do_chunk(bufB, IC<tc * CH>{});
            if constexpr (tc + 2 < NCH) loadbuf(bufB, IC<tc + 2>{});
        }
    });

    // ---- epilogue: NLL (division-free) ----
    const float m0 = P0.x + b_mean[0];
    const float m1 = P0.y + b_mean[1];
    const float m2 = P1.x + b_mean[2];
    const float e0 = P1.y + b_var[0];
    const float e1 = P2.x + b_var[1];
    const float e2 = P2.y + b_var[2];
    const float e3 = P3.x + b_var[3];
    const float e4 = P3.y + b_var[4];
    const float e5 = e5a  + b_var[5];

    const float dv0 = fast_exp2(e3 * LOG2E);
    const float dv1 = fast_exp2(e4 * LOG2E);
    const float dv2 = fast_exp2(e5 * LOG2E);

    const float rt0 = b1x*t0 + b1y*t1 + b1z*t2;
    const float rt1 = b2x*t0 + b2y*t1 + b2z*t2;
    const float rt2 = b3x*t0 + b3y*t1 + b3z*t2;

    const float d0 = m0 - rt0, d1 = m1 - rt1, d2 = m2 - rt2;
    const float y0 = d0;
    const float y1 = d1 - e0 * y0;
    const float y2 = d2 - e1 * y0 - e2 * y1;
    const float quad = y0*y0*fast_rcp(dv0) + y1*y1*fast_rcp(dv1)
                     + y2*y2*fast_rcp(dv2);

    float contrib = 0.5f * (dv0 + dv1 + dv2) + 0.5f * quad;

    #pragma unroll
    for (int off = 32; off > 0; off >>= 1)
        contrib += __shfl_down(contrib, off, 64);
    const int lane = tid & 63, wid = tid >> 6;
    if (lane == 0) wavesum[wid] = contrib;
    __syncthreads();
    if (tid == 0) {
        float s = 0.f;
        #pragma unroll
        for (int w = 0; w < BLOCK / 64; ++w) s += wavesum[w];
        partial[blockIdx.x] = s;
    }
}

__global__ __launch_bounds__(256) void lstm_nll_finalize(
    const float* __restrict__ partial, float* __restrict__ out, int n)
{
    const int tid = threadIdx.x;
    float s = 0.0f;
    for (int i = tid; i < n; i += 256) s += partial[i];
    #pragma unroll
    for (int off = 32; off > 0; off >>= 1)
        s += __shfl_down(s, off, 64);
    __shared__ float wavesum[4];
    const int lane = tid & 63, wid = tid >> 6;
    if (lane == 0) wavesum[wid] = s;
    __syncthreads();
    if (tid == 0) {
        out[0] = (wavesum[0] + wavesum[1] + wavesum[2] + wavesum[3]) *
                 (1.0f / (float)B_TOTAL);
    }
}

extern "C" void kernel_launch(void* const* d_in, const int* in_sizes, int n_in,
                              void* d_out, int out_size, void* d_ws, size_t ws_size,
                              hipStream_t stream) {
    const float* x      = (const float*)d_in[0];
    const float* h0     = (const float*)d_in[1];
    const float* c0     = (const float*)d_in[2];
    const float* target = (const float*)d_in[3];
    const float* W_ih   = (const float*)d_in[4];
    const float* W_hh   = (const float*)d_in[5];
    const float* b_ih   = (const float*)d_in[6];
    const float* b_hh   = (const float*)d_in[7];
    const float* W_mean = (const float*)d_in[8];
    const float* b_mean = (const float*)d_in[9];
    const float* W_var  = (const float*)d_in[10];
    const float* b_var  = (const float*)d_in[11];

    float* partial = (float*)d_ws;  // NBLOCKS floats

    lstm_nll_main<<<NBLOCKS, BLOCK, 0, stream>>>(
        x, h0, c0, target, W_ih, W_hh, b_ih, b_hh,
        W_mean, b_mean, W_var, b_var, partial);
    lstm_nll_finalize<<<1, 256, 0, stream>>>(partial, (float*)d_out, NBLOCKS);
}